// Round 7
// baseline (548.821 us; speedup 1.0000x reference)
//
#include <hip/hip_runtime.h>
#include <hip/hip_bf16.h>
#include <hip/hip_cooperative_groups.h>

namespace cg = cooperative_groups;

// 2-layer GCN on MI355X, round 7.
// r6 lesson: the cooperative launch at a hardcoded 1024 blocks was rejected
// (output stayed zero) -- never launch cooperative without sizing from the
// occupancy API and checking the error. This round: grid-stride phases sized
// by hipOccupancyMaxActiveBlocksPerMultiprocessor (host query, capture-safe),
// plus an error-checked discrete-kernel fallback running the SAME phase code.
// Phases: P0 zero cursor + w2t  | P1 bucket-CSR fill (1 atomic/edge)
//         P2 aggS = (A_hat x)*dinv, d5 = dinv | P3 per-edge relu-folded
//         layer2 (4 fma + fmax + add per edge) -> bf16 tile -> MFMA @ W2.

constexpr int NN = 50000;
constexpr int NE = 800000;
constexpr int CAP = 64;        // in-deg ~ Poisson(16), P(>=64) ~ 1e-20
constexpr int NB_TILE = 3128;  // ceil(50000/16)
constexpr int NTHR = 256;
constexpr int NCU = 256;       // MI355X CUs

typedef __attribute__((ext_vector_type(8))) short bf16x8;
typedef __attribute__((ext_vector_type(4))) float f32x4;

#define ALIGN_UP(x, a) (((x) + (a) - 1) / (a) * (a))

struct Args {
    const float4* x;
    const int4* src4;
    const int4* dst4;
    const float* W1;
    const float* b1;
    const float* W2;
    const float* b2;
    int* cursor;
    int* slots;
    float4* aggS;   // agg4[n] * dinv[n]
    float* d5;      // dinv[n]
    __hip_bfloat16* w2t;
    float* out;
};

__device__ __forceinline__ void do_w2t(const Args& a, int tid) {
    for (int idx = tid; idx < 4096; idx += NTHR) {
        int c = idx >> 6, k = idx & 63;
        a.w2t[idx] = __float2bfloat16(a.W2[k * 64 + c]);
    }
}

__device__ __forceinline__ void do_fill(const Args& a, int i0, int stride) {
    for (int i = i0; i < NE / 4; i += stride) {
        int4 s = a.src4[i];
        int4 d = a.dst4[i];
        int p0 = atomicAdd(&a.cursor[d.x], 1);
        a.slots[d.x * CAP + p0] = s.x;
        int p1 = atomicAdd(&a.cursor[d.y], 1);
        a.slots[d.y * CAP + p1] = s.y;
        int p2 = atomicAdd(&a.cursor[d.z], 1);
        a.slots[d.z * CAP + p2] = s.z;
        int p3 = atomicAdd(&a.cursor[d.w], 1);
        a.slots[d.w * CAP + p3] = s.w;
    }
}

// aggS[n] = (x[n]*di^2 + di*sum x[s]*dinv[s]) * di; d5[n] = di.
// 16 lanes per node group.
__device__ __forceinline__ void do_agg(const Args& a, int grp0, int ngrp, int t) {
    for (int node = grp0; node < NN; node += ngrp) {
        int deg = a.cursor[node];
        float ax = 0.f, ay = 0.f, az = 0.f, aw = 0.f;
        const int* sl = a.slots + node * CAP;
        for (int j = t; j < deg; j += 16) {
            int s = sl[j];
            float4 xs = a.x[s];
            float w = rsqrtf((float)(a.cursor[s] + 1));
            ax = fmaf(xs.x, w, ax);
            ay = fmaf(xs.y, w, ay);
            az = fmaf(xs.z, w, az);
            aw = fmaf(xs.w, w, aw);
        }
#pragma unroll
        for (int o = 8; o >= 1; o >>= 1) {
            ax += __shfl_xor(ax, o);
            ay += __shfl_xor(ay, o);
            az += __shfl_xor(az, o);
            aw += __shfl_xor(aw, o);
        }
        if (t == 0) {
            float di = rsqrtf((float)(deg + 1));
            float di2 = di * di, di3 = di2 * di;
            float4 xs = a.x[node];
            a.aggS[node] = make_float4(fmaf(ax, di2, xs.x * di3),
                                       fmaf(ay, di2, xs.y * di3),
                                       fmaf(az, di2, xs.z * di3),
                                       fmaf(aw, di2, xs.w * di3));
            a.d5[node] = di;
        }
    }
}

// One 16-node tile: phase A per-edge relu-folded message sum (relu(h)*dinv ==
// relu(h*dinv) since dinv>0; self-loop is the edge s=d; *dinv[d] once at the
// end), rows -> bf16 LDS; phase B 2x mfma 16x16x32 bf16 (layouts r3-verified).
__device__ __forceinline__ void do_tile(const Args& a, __hip_bfloat16 (*tile)[72],
                                        int tb, int tid) {
    int wv = tid >> 6, lane = tid & 63;
    float w0 = a.W1[lane], w1 = a.W1[64 + lane];
    float w2 = a.W1[128 + lane], w3 = a.W1[192 + lane];
    float b1c = a.b1[lane];
    int base = tb * 16;
#pragma unroll
    for (int r = 0; r < 4; ++r) {
        int row = wv * 4 + r;
        int node = base + row;
        float acc = 0.f;
        if (node < NN) {
            float4 as = a.aggS[node];
            float ms = fmaf(as.x, w0, fmaf(as.y, w1,
                        fmaf(as.z, w2, fmaf(as.w, w3, b1c * a.d5[node]))));
            acc = fmaxf(ms, 0.f);
            int deg = a.cursor[node];
            const int* sl = a.slots + node * CAP;
            int j = 0;
            for (; j + 3 < deg; j += 4) {
                int4 s4 = *reinterpret_cast<const int4*>(sl + j);
                float4 a0 = a.aggS[s4.x], a1 = a.aggS[s4.y];
                float4 a2 = a.aggS[s4.z], a3 = a.aggS[s4.w];
                float d0 = a.d5[s4.x], d1 = a.d5[s4.y];
                float d2 = a.d5[s4.z], d3 = a.d5[s4.w];
                float m0 = fmaf(a0.x, w0, fmaf(a0.y, w1, fmaf(a0.z, w2, fmaf(a0.w, w3, b1c * d0))));
                float m1 = fmaf(a1.x, w0, fmaf(a1.y, w1, fmaf(a1.z, w2, fmaf(a1.w, w3, b1c * d1))));
                float m2 = fmaf(a2.x, w0, fmaf(a2.y, w1, fmaf(a2.z, w2, fmaf(a2.w, w3, b1c * d2))));
                float m3 = fmaf(a3.x, w0, fmaf(a3.y, w1, fmaf(a3.z, w2, fmaf(a3.w, w3, b1c * d3))));
                acc += fmaxf(m0, 0.f);
                acc += fmaxf(m1, 0.f);
                acc += fmaxf(m2, 0.f);
                acc += fmaxf(m3, 0.f);
            }
            for (; j < deg; ++j) {
                int s0 = sl[j];
                float4 a0 = a.aggS[s0];
                float m0 = fmaf(a0.x, w0, fmaf(a0.y, w1,
                            fmaf(a0.z, w2, fmaf(a0.w, w3, b1c * a.d5[s0]))));
                acc += fmaxf(m0, 0.f);
            }
            acc *= a.d5[node];
        }
        tile[row][lane] = __float2bfloat16(acc);
    }
    __syncthreads();

    int g = lane >> 4, c16 = lane & 15;
    int col = wv * 16 + c16;
    bf16x8 a0 = *reinterpret_cast<const bf16x8*>(&tile[c16][g * 8]);
    bf16x8 a1 = *reinterpret_cast<const bf16x8*>(&tile[c16][32 + g * 8]);
    bf16x8 bb0 = *reinterpret_cast<const bf16x8*>(a.w2t + col * 64 + g * 8);
    bf16x8 bb1 = *reinterpret_cast<const bf16x8*>(a.w2t + col * 64 + 32 + g * 8);
    f32x4 acc4 = {0.f, 0.f, 0.f, 0.f};
    acc4 = __builtin_amdgcn_mfma_f32_16x16x32_bf16(a0, bb0, acc4, 0, 0, 0);
    acc4 = __builtin_amdgcn_mfma_f32_16x16x32_bf16(a1, bb1, acc4, 0, 0, 0);
    float b2v = a.b2[col];
#pragma unroll
    for (int rg = 0; rg < 4; ++rg) {
        int node = base + g * 4 + rg;
        if (node < NN) a.out[node * 64 + col] = fmaxf(acc4[rg] + b2v, 0.f);
    }
    __syncthreads();  // tile may be reused by caller's next iteration
}

// ---- cooperative single-kernel path (grid size = runtime-computed) ----
__global__ __launch_bounds__(NTHR, 4) void gcn_fused(Args a) {
    cg::grid_group grid = cg::this_grid();
    const int tid = threadIdx.x, bid = blockIdx.x, nb = gridDim.x;
    const int gthr = bid * NTHR + tid, gsz = nb * NTHR;

    for (int i = gthr; i < NN; i += gsz) a.cursor[i] = 0;
    if (bid == 0) do_w2t(a, tid);
    grid.sync();

    do_fill(a, gthr, gsz);
    grid.sync();

    do_agg(a, gthr >> 4, gsz >> 4, tid & 15);
    grid.sync();

    __shared__ __hip_bfloat16 tile[16][72];
    for (int tb = bid; tb < NB_TILE; tb += nb) do_tile(a, tile, tb, tid);
}

// ---- discrete fallback path (same phase code, kernel-boundary syncs) ----
__global__ __launch_bounds__(NTHR) void k_fill(Args a) {
    if (blockIdx.x == 0) do_w2t(a, threadIdx.x);
    do_fill(a, blockIdx.x * NTHR + threadIdx.x, gridDim.x * NTHR);
}
__global__ __launch_bounds__(NTHR) void k_agg(Args a) {
    int gthr = blockIdx.x * NTHR + threadIdx.x;
    do_agg(a, gthr >> 4, (gridDim.x * NTHR) >> 4, threadIdx.x & 15);
}
__global__ __launch_bounds__(NTHR) void k_l2(Args a) {
    __shared__ __hip_bfloat16 tile[16][72];
    do_tile(a, tile, blockIdx.x, threadIdx.x);
}

extern "C" void kernel_launch(void* const* d_in, const int* in_sizes, int n_in,
                              void* d_out, int out_size, void* d_ws, size_t ws_size,
                              hipStream_t stream) {
    const float* x  = (const float*)d_in[0];
    const int*   ei = (const int*)d_in[1];  // [2, NE]: src row then dst row
    const float* W1 = (const float*)d_in[2];
    const float* b1 = (const float*)d_in[3];
    const float* W2 = (const float*)d_in[4];
    const float* b2 = (const float*)d_in[5];

    char* w = (char*)d_ws;
    auto take = [&](size_t bytes) { char* p = w; w += ALIGN_UP(bytes, 256); return p; };
    int*   cursor = (int*)  take((size_t)NN * 4);
    int*   slots  = (int*)  take((size_t)NN * CAP * 4);  // 12.8 MB
    float* aggS   = (float*)take((size_t)NN * 16);
    float* d5     = (float*)take((size_t)NN * 4);
    __hip_bfloat16* w2t = (__hip_bfloat16*)take(4096 * 2);

    Args args;
    args.x = (const float4*)x;
    args.src4 = (const int4*)ei;
    args.dst4 = (const int4*)(ei + NE);
    args.W1 = W1; args.b1 = b1; args.W2 = W2; args.b2 = b2;
    args.cursor = cursor; args.slots = slots;
    args.aggS = (float4*)aggS; args.d5 = d5; args.w2t = w2t;
    args.out = (float*)d_out;

    // Admission-safe cooperative sizing: pure host-side query (not stream-
    // ordered -> graph-capture-safe, deterministic across calls).
    int maxBlkPerCU = 0;
    hipError_t qe = hipOccupancyMaxActiveBlocksPerMultiprocessor(
        &maxBlkPerCU, gcn_fused, NTHR, 0);
    if (qe == hipSuccess && maxBlkPerCU >= 1) {
        int nblk = maxBlkPerCU * NCU;
        if (nblk > 1024) nblk = 1024;
        void* params[] = { &args };
        hipError_t le = hipLaunchCooperativeKernel(
            gcn_fused, dim3(nblk), dim3(NTHR), params, 0, stream);
        if (le == hipSuccess) return;
    }

    // Fallback: identical phase code as 4 discrete dispatches.
    hipMemsetAsync(cursor, 0, (size_t)NN * 4, stream);
    k_fill<<<(NE / 4 + NTHR - 1) / NTHR, NTHR, 0, stream>>>(args);   // 782
    k_agg<<<NN / 16, NTHR, 0, stream>>>(args);                        // 3125
    k_l2<<<NB_TILE, NTHR, 0, stream>>>(args);
}

// Round 8
// 174.370 us; speedup vs baseline: 3.1474x; 3.1474x over previous
//
#include <hip/hip_runtime.h>
#include <hip/hip_bf16.h>

// 2-layer GCN on MI355X, round 8.
// r7 lesson: grid.sync() costs ~100us/sync on 8-XCD gfx950 -> cooperative
// mega-kernel abandoned. This round: r5's 4-dispatch structure + r7's
// layer2 algebra (per-edge = 5 fma + fmax + add via aggS/d5 precompute;
// relu(h)*dinv == relu(h*dinv) since dinv>0) + ushort slots (src<65536,
// halves bucket scatter-write traffic).
//   memset cursor -> k_fill(+w2t) -> k_agg (aggS,d5) -> k_l2 (tile+MFMA)

constexpr int NN = 50000;
constexpr int NE = 800000;
constexpr int CAP = 64;        // in-deg ~ Poisson(16); P(any node >= 65) ~ 1e-15
constexpr int NB_TILE = 3128;  // ceil(50000/16)
constexpr int NTHR = 256;

typedef __attribute__((ext_vector_type(8))) short bf16x8;
typedef __attribute__((ext_vector_type(4))) float f32x4;

#define ALIGN_UP(x, a) (((x) + (a) - 1) / (a) * (a))

struct Args {
    const float4* x;
    const int4* src4;
    const int4* dst4;
    const float* W1;
    const float* b1;
    const float* W2;
    const float* b2;
    int* cursor;
    unsigned short* slots;   // src ids fit in 16 bits (NN < 65536)
    float4* aggS;            // (A_hat x)[n] * dinv[n]
    float* d5;               // dinv[n]
    __hip_bfloat16* w2t;     // w2t[c][k] = bf16(W2[k][c])
    float* out;
};

// Bucket-CSR fill: 1 int atomic per edge, 2B slot store. Block 0 builds w2t.
__global__ __launch_bounds__(NTHR) void k_fill(Args a) {
    int i = blockIdx.x * NTHR + threadIdx.x;
    if (i < NE / 4) {
        int4 s = a.src4[i];
        int4 d = a.dst4[i];
        int p0 = atomicAdd(&a.cursor[d.x], 1);
        a.slots[d.x * CAP + p0] = (unsigned short)s.x;
        int p1 = atomicAdd(&a.cursor[d.y], 1);
        a.slots[d.y * CAP + p1] = (unsigned short)s.y;
        int p2 = atomicAdd(&a.cursor[d.z], 1);
        a.slots[d.z * CAP + p2] = (unsigned short)s.z;
        int p3 = atomicAdd(&a.cursor[d.w], 1);
        a.slots[d.w * CAP + p3] = (unsigned short)s.w;
    }
    if (blockIdx.x == 0) {
        for (int idx = threadIdx.x; idx < 4096; idx += NTHR) {
            int c = idx >> 6, k = idx & 63;
            a.w2t[idx] = __float2bfloat16(a.W2[k * 64 + c]);
        }
    }
}

// aggS[n] = (x[n]*di^2 + di * sum_s x[s]*dinv[s]) * di;  d5[n] = di.
// 16 lanes per node, 4 nodes per wave.
__global__ __launch_bounds__(NTHR) void k_agg(Args a) {
    int tid = threadIdx.x;
    int t = tid & 15;
    int node = (blockIdx.x * NTHR + tid) >> 4;  // grid sized exactly: NN/16 blocks
    int deg = a.cursor[node];
    float ax = 0.f, ay = 0.f, az = 0.f, aw = 0.f;
    const unsigned short* sl = a.slots + node * CAP;
    for (int j = t; j < deg; j += 16) {
        int s = sl[j];
        float4 xs = a.x[s];
        float w = rsqrtf((float)(a.cursor[s] + 1));
        ax = fmaf(xs.x, w, ax);
        ay = fmaf(xs.y, w, ay);
        az = fmaf(xs.z, w, az);
        aw = fmaf(xs.w, w, aw);
    }
#pragma unroll
    for (int o = 8; o >= 1; o >>= 1) {
        ax += __shfl_xor(ax, o);
        ay += __shfl_xor(ay, o);
        az += __shfl_xor(az, o);
        aw += __shfl_xor(aw, o);
    }
    if (t == 0) {
        float di = rsqrtf((float)(deg + 1));
        float di2 = di * di, di3 = di2 * di;
        float4 xs = a.x[node];
        a.aggS[node] = make_float4(fmaf(ax, di2, xs.x * di3),
                                   fmaf(ay, di2, xs.y * di3),
                                   fmaf(az, di2, xs.z * di3),
                                   fmaf(aw, di2, xs.w * di3));
        a.d5[node] = di;
    }
}

// Layer 2 fused; 256-thread block = one 16-node tile, wave wv owns rows
// wv*4..+3 (lane = h1-channel) then MFMA col-tile wv.
// Per edge: m = aggS[s].W1col + b1c*d5[s]; acc += relu(m). Self-loop is the
// edge s=d. Final acc *= d5[node]. Then bf16 LDS tile -> 2x mfma 16x16x32.
__global__ __launch_bounds__(NTHR) void k_l2(Args a) {
    __shared__ __hip_bfloat16 tile[16][72];
    int tid = threadIdx.x;
    int wv = tid >> 6, lane = tid & 63;
    float w0 = a.W1[lane], w1 = a.W1[64 + lane];
    float w2 = a.W1[128 + lane], w3 = a.W1[192 + lane];
    float b1c = a.b1[lane];
    int base = blockIdx.x * 16;
#pragma unroll
    for (int r = 0; r < 4; ++r) {
        int row = wv * 4 + r;
        int node = base + row;
        float acc = 0.f;
        if (node < NN) {
            float4 as = a.aggS[node];
            float ms = fmaf(as.x, w0, fmaf(as.y, w1,
                        fmaf(as.z, w2, fmaf(as.w, w3, b1c * a.d5[node]))));
            acc = fmaxf(ms, 0.f);
            int deg = a.cursor[node];
            const unsigned short* sl = a.slots + node * CAP;
            int j = 0;
            for (; j + 3 < deg; j += 4) {
                ushort4 s4 = *reinterpret_cast<const ushort4*>(sl + j);
                float4 a0 = a.aggS[s4.x], a1 = a.aggS[s4.y];
                float4 a2 = a.aggS[s4.z], a3 = a.aggS[s4.w];
                float d0 = a.d5[s4.x], d1 = a.d5[s4.y];
                float d2 = a.d5[s4.z], d3 = a.d5[s4.w];
                float m0 = fmaf(a0.x, w0, fmaf(a0.y, w1, fmaf(a0.z, w2, fmaf(a0.w, w3, b1c * d0))));
                float m1 = fmaf(a1.x, w0, fmaf(a1.y, w1, fmaf(a1.z, w2, fmaf(a1.w, w3, b1c * d1))));
                float m2 = fmaf(a2.x, w0, fmaf(a2.y, w1, fmaf(a2.z, w2, fmaf(a2.w, w3, b1c * d2))));
                float m3 = fmaf(a3.x, w0, fmaf(a3.y, w1, fmaf(a3.z, w2, fmaf(a3.w, w3, b1c * d3))));
                acc += fmaxf(m0, 0.f);
                acc += fmaxf(m1, 0.f);
                acc += fmaxf(m2, 0.f);
                acc += fmaxf(m3, 0.f);
            }
            for (; j < deg; ++j) {
                int s0 = sl[j];
                float4 a0 = a.aggS[s0];
                float m0 = fmaf(a0.x, w0, fmaf(a0.y, w1,
                            fmaf(a0.z, w2, fmaf(a0.w, w3, b1c * a.d5[s0]))));
                acc += fmaxf(m0, 0.f);
            }
            acc *= a.d5[node];
        }
        tile[row][lane] = __float2bfloat16(acc);
    }
    __syncthreads();

    // MFMA epilogue (fragment layouts verified end-to-end r3-r5).
    int g = lane >> 4, c16 = lane & 15;
    int col = wv * 16 + c16;
    bf16x8 a0 = *reinterpret_cast<const bf16x8*>(&tile[c16][g * 8]);
    bf16x8 a1 = *reinterpret_cast<const bf16x8*>(&tile[c16][32 + g * 8]);
    bf16x8 bb0 = *reinterpret_cast<const bf16x8*>(a.w2t + col * 64 + g * 8);
    bf16x8 bb1 = *reinterpret_cast<const bf16x8*>(a.w2t + col * 64 + 32 + g * 8);
    f32x4 acc4 = {0.f, 0.f, 0.f, 0.f};
    acc4 = __builtin_amdgcn_mfma_f32_16x16x32_bf16(a0, bb0, acc4, 0, 0, 0);
    acc4 = __builtin_amdgcn_mfma_f32_16x16x32_bf16(a1, bb1, acc4, 0, 0, 0);
    float b2v = a.b2[col];
#pragma unroll
    for (int rg = 0; rg < 4; ++rg) {
        int node = base + g * 4 + rg;
        if (node < NN) a.out[node * 64 + col] = fmaxf(acc4[rg] + b2v, 0.f);
    }
}

extern "C" void kernel_launch(void* const* d_in, const int* in_sizes, int n_in,
                              void* d_out, int out_size, void* d_ws, size_t ws_size,
                              hipStream_t stream) {
    const float* x  = (const float*)d_in[0];
    const int*   ei = (const int*)d_in[1];  // [2, NE]: src row then dst row
    const float* W1 = (const float*)d_in[2];
    const float* b1 = (const float*)d_in[3];
    const float* W2 = (const float*)d_in[4];
    const float* b2 = (const float*)d_in[5];

    char* w = (char*)d_ws;
    auto take = [&](size_t bytes) { char* p = w; w += ALIGN_UP(bytes, 256); return p; };
    int*            cursor = (int*)           take((size_t)NN * 4);
    unsigned short* slots  = (unsigned short*)take((size_t)NN * CAP * 2);  // 6.4 MB
    float*          aggS   = (float*)         take((size_t)NN * 16);
    float*          d5     = (float*)         take((size_t)NN * 4);
    __hip_bfloat16* w2t    = (__hip_bfloat16*)take(4096 * 2);

    Args args;
    args.x = (const float4*)x;
    args.src4 = (const int4*)ei;
    args.dst4 = (const int4*)(ei + NE);
    args.W1 = W1; args.b1 = b1; args.W2 = W2; args.b2 = b2;
    args.cursor = cursor; args.slots = slots;
    args.aggS = (float4*)aggS; args.d5 = d5; args.w2t = w2t;
    args.out = (float*)d_out;

    hipMemsetAsync(cursor, 0, (size_t)NN * 4, stream);
    k_fill<<<(NE / 4 + NTHR - 1) / NTHR, NTHR, 0, stream>>>(args);  // 782
    k_agg<<<NN / 16, NTHR, 0, stream>>>(args);                      // 3125
    k_l2<<<NB_TILE, NTHR, 0, stream>>>(args);
}